// Round 1
// baseline (93.570 us; speedup 1.0000x reference)
//
#include <hip/hip_runtime.h>

#define D_MODEL 2048
#define N_EXP 8
#define TOPK 2

// One wave (64 lanes) per token. W staged in LDS (64 KB). Lane i covers
// elements [ (lane + j*64)*4 .. +3 ] for j in 0..7 -> coalesced float4 loads.
__global__ __launch_bounds__(256) void moe_gate_kernel(
    const float* __restrict__ H, const float* __restrict__ W,
    float* __restrict__ out_idx, float* __restrict__ out_prob,
    unsigned int* __restrict__ counts, int n_tokens)
{
    __shared__ float wlds[N_EXP * D_MODEL];  // 64 KB
    __shared__ unsigned int hist[N_EXP];

    const int tid = threadIdx.x;

    // Stage W into LDS, vectorized. 8*2048/4 = 4096 float4s, 256 threads -> 16 each.
    const float4* W4 = reinterpret_cast<const float4*>(W);
    float4* wl4 = reinterpret_cast<float4*>(wlds);
#pragma unroll
    for (int i = 0; i < (N_EXP * D_MODEL / 4) / 256; ++i)
        wl4[tid + i * 256] = W4[tid + i * 256];
    if (tid < N_EXP) hist[tid] = 0u;
    __syncthreads();

    const int lane = tid & 63;
    const int wid = tid >> 6;
    const int gwave = blockIdx.x * (blockDim.x >> 6) + wid;
    const int nwave = gridDim.x * (blockDim.x >> 6);

    for (int t = gwave; t < n_tokens; t += nwave) {
        const float4* h4 = reinterpret_cast<const float4*>(H + (size_t)t * D_MODEL);
        float acc[N_EXP];
#pragma unroll
        for (int e = 0; e < N_EXP; ++e) acc[e] = 0.f;

#pragma unroll
        for (int j = 0; j < D_MODEL / 4 / 64; ++j) {  // 8 chunks
            float4 h = h4[lane + j * 64];
#pragma unroll
            for (int e = 0; e < N_EXP; ++e) {
                float4 w = wl4[e * (D_MODEL / 4) + lane + j * 64];
                acc[e] = fmaf(h.x, w.x, acc[e]);
                acc[e] = fmaf(h.y, w.y, acc[e]);
                acc[e] = fmaf(h.z, w.z, acc[e]);
                acc[e] = fmaf(h.w, w.w, acc[e]);
            }
        }

        // Butterfly reduce each expert's partial across the 64-lane wave.
#pragma unroll
        for (int e = 0; e < N_EXP; ++e) {
            float v = acc[e];
#pragma unroll
            for (int s = 1; s < 64; s <<= 1) v += __shfl_xor(v, s, 64);
            acc[e] = v;
        }

        if (lane == 0) {
            // softmax over 8 logits (fp32, expf for accuracy vs np reference)
            float m = acc[0];
#pragma unroll
            for (int e = 1; e < N_EXP; ++e) m = fmaxf(m, acc[e]);
            float p[N_EXP];
            float s = 0.f;
#pragma unroll
            for (int e = 0; e < N_EXP; ++e) { p[e] = expf(acc[e] - m); s += p[e]; }
            const float inv = 1.f / s;

            // top-2, ties -> lowest index (strict > like jax.lax.top_k)
            float v1 = -INFINITY, v2 = -INFINITY;
            int i1 = 0, i2 = 0;
#pragma unroll
            for (int e = 0; e < N_EXP; ++e) {
                float v = acc[e];
                if (v > v1) { v2 = v1; i2 = i1; v1 = v; i1 = e; }
                else if (v > v2) { v2 = v; i2 = e; }
            }

            out_idx[2 * t + 0] = (float)i1;
            out_idx[2 * t + 1] = (float)i2;
            out_prob[2 * t + 0] = p[i1] * inv;
            out_prob[2 * t + 1] = p[i2] * inv;
            atomicAdd(&hist[i1], 1u);
            atomicAdd(&hist[i2], 1u);
        }
    }

    __syncthreads();
    if (tid < N_EXP) atomicAdd(&counts[tid], hist[tid]);
}

__global__ void zero_counts_kernel(unsigned int* counts)
{
    if (threadIdx.x < N_EXP) counts[threadIdx.x] = 0u;
}

__global__ void finalize_kernel(const unsigned int* __restrict__ counts,
                                float* __restrict__ out_aux,
                                float* __restrict__ out_load, int n_tokens)
{
    if (threadIdx.x == 0) {
        const float denom = 1.0f / (float)(n_tokens * TOPK);
        float load[N_EXP];
        float sum = 0.f;
        for (int e = 0; e < N_EXP; ++e) { load[e] = (float)counts[e] * denom; sum += load[e]; }
        const float mean = sum / (float)N_EXP;
        float var = 0.f;
        for (int e = 0; e < N_EXP; ++e) { float d = load[e] - mean; var += d * d; }
        var /= (float)N_EXP;
        const float cv_sq = var / (mean * mean + 1e-9f);
        out_aux[0] = 0.01f * cv_sq;
        for (int e = 0; e < N_EXP; ++e) out_load[e] = load[e];
    }
}

extern "C" void kernel_launch(void* const* d_in, const int* in_sizes, int n_in,
                              void* d_out, int out_size, void* d_ws, size_t ws_size,
                              hipStream_t stream)
{
    const float* H = (const float*)d_in[0];
    const float* W = (const float*)d_in[1];
    const int n_tokens = in_sizes[0] / D_MODEL;  // 4*4096 = 16384

    float* out = (float*)d_out;
    // Output layout (concatenated return tuple, all fp32):
    // [0, 2N)       top_indices (as floats)
    // [2N, 4N)      top_probs
    // [4N]          aux_loss
    // [4N+1, 4N+9)  load
    float* out_idx = out;
    float* out_prob = out + 2 * (size_t)n_tokens;
    float* out_aux = out + 4 * (size_t)n_tokens;
    float* out_load = out + 4 * (size_t)n_tokens + 1;

    unsigned int* counts = (unsigned int*)d_ws;

    hipLaunchKernelGGL(zero_counts_kernel, dim3(1), dim3(64), 0, stream, counts);

    const int grid = 512;  // 2 blocks/CU (128 KB LDS/CU), 8 waves/CU
    hipLaunchKernelGGL(moe_gate_kernel, dim3(grid), dim3(256), 0, stream,
                       H, W, out_idx, out_prob, counts, n_tokens);

    hipLaunchKernelGGL(finalize_kernel, dim3(1), dim3(64), 0, stream,
                       counts, out_aux, out_load, n_tokens);
}

// Round 2
// 63.553 us; speedup vs baseline: 1.4723x; 1.4723x over previous
//
#include <hip/hip_runtime.h>

#define D_MODEL 2048
#define N_EXP 8
#define TOPK 2
#define TPG 4  // tokens per wave

// One wave handles TPG=4 tokens. Lane owns a 4-float slice per 256-elem chunk.
// W read straight from global (64 KB, L2-resident) -- no LDS, so occupancy is
// VGPR-bound: __launch_bounds__(256,4) => <=128 VGPR => 4 waves/SIMD.
__global__ __launch_bounds__(256, 4) void moe_gate_kernel(
    const float* __restrict__ H, const float* __restrict__ W,
    float* __restrict__ out_idx, float* __restrict__ out_prob,
    unsigned int* __restrict__ counts, int n_tokens)
{
    __shared__ unsigned int hist[N_EXP];
    const int tid = threadIdx.x;
    if (tid < N_EXP) hist[tid] = 0u;
    __syncthreads();

    const int lane = tid & 63;
    const int wid = tid >> 6;
    const int gwave = blockIdx.x * (blockDim.x >> 6) + wid;
    const int t_base = gwave * TPG;

    if (t_base < n_tokens) {
        const float4* W4 = reinterpret_cast<const float4*>(W);

        float val[TPG * N_EXP];
#pragma unroll
        for (int v = 0; v < TPG * N_EXP; ++v) val[v] = 0.f;

#pragma unroll 2
        for (int j = 0; j < D_MODEL / 4 / 64; ++j) {  // 8 chunks of 256 elems
            float4 w[N_EXP];
#pragma unroll
            for (int e = 0; e < N_EXP; ++e)
                w[e] = W4[e * (D_MODEL / 4) + j * 64 + lane];
#pragma unroll
            for (int t = 0; t < TPG; ++t) {
                const float4 h = *reinterpret_cast<const float4*>(
                    H + (size_t)(t_base + t) * D_MODEL + (size_t)(j * 64 + lane) * 4);
#pragma unroll
                for (int e = 0; e < N_EXP; ++e) {
                    float a = val[t * N_EXP + e];
                    a = fmaf(h.x, w[e].x, a);
                    a = fmaf(h.y, w[e].y, a);
                    a = fmaf(h.z, w[e].z, a);
                    a = fmaf(h.w, w[e].w, a);
                    val[t * N_EXP + e] = a;
                }
            }
        }

        // Fold-reduce: 32 per-lane partials -> each lane ends with ONE
        // (token,expert) logit summed over all 64 lanes.
        // After 5 folds lane holds orig index v = 16*b0+8*b1+4*b2+2*b3+b4
        // (b_k = bit k of lane), summed over its 32-lane half; the final
        // xor-32 butterfly completes the sum (lanes l and l^32 duplicate).
        int c = TPG * N_EXP;
#pragma unroll
        for (int k = 0; k < 5; ++k) {
            const int m = 1 << k;
            const int half = c >> 1;
            const bool hi = (lane & m) != 0;
#pragma unroll
            for (int i = 0; i < half; ++i) {
                float keep = hi ? val[i + half] : val[i];
                float send = hi ? val[i] : val[i + half];
                val[i] = keep + __shfl_xor(send, m, 64);
            }
            c = half;
        }
        float logit = val[0] + __shfl_xor(val[0], 32, 64);

        // v = t*8 + e ; t = 2*b0 + b1 ; e = 4*b2 + 2*b3 + b4.
        const int e = (((lane >> 2) & 1) << 2) | (((lane >> 3) & 1) << 1) | ((lane >> 4) & 1);

        // Softmax across the 8 experts of this lane's token: the 8 lanes
        // sharing (b0,b1) within a 32-half differ in bits 2..4 -> masks 4,8,16.
        float mx = logit;
        mx = fmaxf(mx, __shfl_xor(mx, 4, 64));
        mx = fmaxf(mx, __shfl_xor(mx, 8, 64));
        mx = fmaxf(mx, __shfl_xor(mx, 16, 64));
        float p = expf(logit - mx);
        float s = p;
        s += __shfl_xor(s, 4, 64);
        s += __shfl_xor(s, 8, 64);
        s += __shfl_xor(s, 16, 64);
        const float inv = 1.f / s;

        // Top-1 argmax with payload (logit,e,p); ties -> lowest index.
        float v1 = logit; int i1 = e; float p1 = p;
#pragma unroll
        for (int st = 0; st < 3; ++st) {
            const int m = 4 << st;
            float ov = __shfl_xor(v1, m, 64);
            int oi = __shfl_xor(i1, m, 64);
            float op = __shfl_xor(p1, m, 64);
            if (ov > v1 || (ov == v1 && oi < i1)) { v1 = ov; i1 = oi; p1 = op; }
        }
        // Top-2: mask out winner, argmax again.
        float v2 = (e == i1) ? -INFINITY : logit;
        int i2 = e; float p2 = p;
#pragma unroll
        for (int st = 0; st < 3; ++st) {
            const int m = 4 << st;
            float ov = __shfl_xor(v2, m, 64);
            int oi = __shfl_xor(i2, m, 64);
            float op = __shfl_xor(p2, m, 64);
            if (ov > v2 || (ov == v2 && oi < i2)) { v2 = ov; i2 = oi; p2 = op; }
        }

        // Writers: lane with e-bits==0, b5==0 for each token.
        // lane 0 -> t_loc 0, lane 1 -> 2, lane 2 -> 1, lane 3 -> 3.
        if (lane < TPG) {
            const int t_loc = ((lane & 1) << 1) | ((lane >> 1) & 1);
            const int t = t_base + t_loc;
            if (t < n_tokens) {
                out_idx[2 * t + 0] = (float)i1;
                out_idx[2 * t + 1] = (float)i2;
                out_prob[2 * t + 0] = p1 * inv;
                out_prob[2 * t + 1] = p2 * inv;
                atomicAdd(&hist[i1], 1u);
                atomicAdd(&hist[i2], 1u);
            }
        }
    }

    __syncthreads();
    if (tid < N_EXP) atomicAdd(&counts[tid], hist[tid]);
}

__global__ void zero_counts_kernel(unsigned int* counts)
{
    if (threadIdx.x < N_EXP) counts[threadIdx.x] = 0u;
}

__global__ void finalize_kernel(const unsigned int* __restrict__ counts,
                                float* __restrict__ out_aux,
                                float* __restrict__ out_load, int n_tokens)
{
    if (threadIdx.x == 0) {
        const float denom = 1.0f / (float)(n_tokens * TOPK);
        float load[N_EXP];
        float sum = 0.f;
        for (int e = 0; e < N_EXP; ++e) { load[e] = (float)counts[e] * denom; sum += load[e]; }
        const float mean = sum / (float)N_EXP;
        float var = 0.f;
        for (int e = 0; e < N_EXP; ++e) { float d = load[e] - mean; var += d * d; }
        var /= (float)N_EXP;
        const float cv_sq = var / (mean * mean + 1e-9f);
        out_aux[0] = 0.01f * cv_sq;
        for (int e = 0; e < N_EXP; ++e) out_load[e] = load[e];
    }
}

extern "C" void kernel_launch(void* const* d_in, const int* in_sizes, int n_in,
                              void* d_out, int out_size, void* d_ws, size_t ws_size,
                              hipStream_t stream)
{
    const float* H = (const float*)d_in[0];
    const float* W = (const float*)d_in[1];
    const int n_tokens = in_sizes[0] / D_MODEL;  // 16384

    float* out = (float*)d_out;
    float* out_idx = out;
    float* out_prob = out + 2 * (size_t)n_tokens;
    float* out_aux = out + 4 * (size_t)n_tokens;
    float* out_load = out + 4 * (size_t)n_tokens + 1;

    unsigned int* counts = (unsigned int*)d_ws;

    hipLaunchKernelGGL(zero_counts_kernel, dim3(1), dim3(64), 0, stream, counts);

    // 16384 tokens / (4 tokens/wave) = 4096 waves = 1024 blocks of 4 waves.
    const int waves_needed = (n_tokens + TPG - 1) / TPG;
    const int grid = (waves_needed + 3) / 4;
    hipLaunchKernelGGL(moe_gate_kernel, dim3(grid), dim3(256), 0, stream,
                       H, W, out_idx, out_prob, counts, n_tokens);

    hipLaunchKernelGGL(finalize_kernel, dim3(1), dim3(64), 0, stream,
                       counts, out_aux, out_load, n_tokens);
}